// Round 13
// baseline (320.508 us; speedup 1.0000x reference)
//
#include <hip/hip_runtime.h>

// q = rownorm( 1 / (1 + ||x - c||^2) ), ALPHA=1
// x: (262144, 256) f32 ; clusters: (256, 256) f32 ; out: (262144, 256) f32
//
// R13: R10's per-pair structure (col-split wave pairs, pairwise LDS-flag
// sync, xv2-mid/xv1-late pipeline, rcpf epilogue — 124 VGPR no-spill) with
// 12 waves/block (768 thr) instead of 8. R10's occupancy (22%) was
// grid/LDS-limited (1 block/CU x 8 waves), NOT register-limited: 124 regs
// fits 12 waves/CU easily (1488 <= 2048). The work unit is an independent
// 16-row strip per 2-wave pair, so pair count is decoupled from tiling:
// 1536 pairs deal 16384 strips round-robin (10-11 each, ~3% tail).
// 3 waves/SIMD = +50% latency hiding at the same register budget.
// (R12 lesson: deeper prefetch hurt — reverted to R10's exact pipeline.)

#define NROWS 262144
#define DDIM  256
#define KCL   256
#define GRID  256
#define PPB   6                        // pairs per block (12 waves)
#define NPAIRS (GRID * PPB)            // 1536
#define NSTRIPS (NROWS / 16)           // 16384
#define BASEK (NSTRIPS / NPAIRS)       // 10
#define EXTRA (NSTRIPS % NPAIRS)       // 1024 pairs get one extra strip

using f32x4  = __attribute__((ext_vector_type(4))) float;
using s16x8  = __attribute__((ext_vector_type(8))) short;

__device__ inline unsigned short f2bf(float f) {
    // round-to-nearest-even f32 -> bf16
    unsigned int u = __float_as_uint(f);
    u += 0x7fffu + ((u >> 16) & 1u);
    return (unsigned short)(u >> 16);
}

// One wave per cluster row: convert to bf16, compute ||c||^2.
__global__ void prep_kernel(const float* __restrict__ clusters,
                            unsigned short* __restrict__ cb,
                            float* __restrict__ csq) {
    int k    = blockIdx.x;
    int lane = threadIdx.x;  // 64 threads
    const float* row = clusters + (size_t)k * DDIM;
    float4 a = *reinterpret_cast<const float4*>(row + lane * 4);
    ushort4 b;
    b.x = f2bf(a.x); b.y = f2bf(a.y); b.z = f2bf(a.z); b.w = f2bf(a.w);
    *reinterpret_cast<ushort4*>(cb + (size_t)k * DDIM + lane * 4) = b;
    float ss = a.x*a.x + a.y*a.y + a.z*a.z + a.w*a.w;
    #pragma unroll
    for (int m = 1; m < 64; m <<= 1) ss += __shfl_xor(ss, m);
    if (lane == 0) csq[k] = ss;
}

// 12 waves/block: wave w -> rg = w>>1 (pair 0..5), ch = w&1 (col half).
// Pair g = blockIdx*6+rg handles strips s = g + 1536*k (16 rows each);
// within the pair, wave computes 16 rows x cols [ch*128, +128).
// A-frag: lane holds x[row + (l&15)][s*32 + (l>>4)*8 + j], j=0..7
// B-frag: lane holds c[ch*128 + f*16 + (l&15)][s*32 + (l>>4)*8 + j], f=0..7
// C/D   : col = l&15, row = (l>>4)*4 + reg   [verified layout, m89]
__global__ __launch_bounds__(768, 2) void fused_kernel(
    const float* __restrict__ x,
    const unsigned short* __restrict__ cb,
    const float* __restrict__ csq,
    float* __restrict__ out) {

    __shared__ char  lds_b[KCL * DDIM * 2];   // 128 KB: full B, swizzled
    __shared__ float ls_sum[2][2][PPB][16];   // [k&1][ch][rg][row] partials
    __shared__ int   ls_flag[2][PPB];         // [ch][rg] strips-completed

    const int tid  = threadIdx.x;
    const int lane = tid & 63;
    const int wave = tid >> 6;               // 0..11
    const int rg   = wave >> 1;              // 0..5
    const int ch   = wave & 1;               // 0..1
    const int c15  = lane & 15;
    const int kch  = lane >> 4;              // 0..3

    const int g  = blockIdx.x * PPB + rg;          // global pair id
    const int nk = BASEK + (g < EXTRA ? 1 : 0);    // strips for this pair

    // ---- stage full B into LDS (waves 0..7; linear dest, swizzled src) ----
    if (wave < 8) {
        #pragma unroll
        for (int it = 0; it < 16; ++it) {
            int slot = it * 8192 + tid * 16;
            int src  = slot ^ (((slot >> 9) & 7) << 4);
            __builtin_amdgcn_global_load_lds(
                (const __attribute__((address_space(1))) unsigned int*)((const char*)cb + src),
                (__attribute__((address_space(3))) unsigned int*)(lds_b + slot),
                16, 0, 0);
        }
    }

    if (tid < 2 * PPB) ((int*)ls_flag)[tid] = 0;

    // csq fragment for this wave's col half (8 regs)
    float cs[8];
    #pragma unroll
    for (int f = 0; f < 8; ++f) cs[f] = csq[ch * 128 + f * 16 + c15];

    __syncthreads();   // drains vmcnt; B + flags ready (only block barrier)

    // per-lane x base for strip iteration k
    auto xrow = [&](int k) -> const float* {
        return x + (size_t)((g + NPAIRS * k) * 16 + c15) * DDIM + kch * 8;
    };

    f32x4 xv1[8], xv2[8];

    // ---- prologue: issue strip 0's first k-half (flies under B staging) ----
    {
        const float* xr = xrow(0);
        #pragma unroll
        for (int i = 0; i < 8; ++i)
            xv1[i] = *reinterpret_cast<const f32x4*>(xr + (i >> 1) * 32 + (i & 1) * 4);
    }

    #pragma unroll 1
    for (int k = 0; k < nk; ++k) {
        const int row0t = (g + NPAIRS * k) * 16;
        const float* xr = xrow(k);

        s16x8 afrag[8];
        float p[4] = {0.f, 0.f, 0.f, 0.f};

        // ---- convert batch 1 (k 0..127) -> afrag[0..3] ----
        #pragma unroll
        for (int s4 = 0; s4 < 4; ++s4) {
            f32x4 xa = xv1[2 * s4], xb = xv1[2 * s4 + 1];
            float t0 = xa[0]*xa[0] + xa[1]*xa[1];
            float t1 = xa[2]*xa[2] + xa[3]*xa[3];
            float t2 = xb[0]*xb[0] + xb[1]*xb[1];
            float t3 = xb[2]*xb[2] + xb[3]*xb[3];
            p[s4] += (t0 + t1) + (t2 + t3);
            afrag[s4][0] = (short)f2bf(xa[0]); afrag[s4][1] = (short)f2bf(xa[1]);
            afrag[s4][2] = (short)f2bf(xa[2]); afrag[s4][3] = (short)f2bf(xa[3]);
            afrag[s4][4] = (short)f2bf(xb[0]); afrag[s4][5] = (short)f2bf(xb[1]);
            afrag[s4][6] = (short)f2bf(xb[2]); afrag[s4][7] = (short)f2bf(xb[3]);
        }

        // ---- issue batch 2 (k 128..255); MFMA s=0..3 covers its latency ----
        #pragma unroll
        for (int i = 0; i < 8; ++i) {
            int ii = 8 + i;
            xv2[i] = *reinterpret_cast<const f32x4*>(xr + (ii >> 1) * 32 + (ii & 1) * 4);
        }

        f32x4 acc[8];
        #pragma unroll
        for (int f = 0; f < 8; ++f) acc[f] = (f32x4){0.f, 0.f, 0.f, 0.f};

        #pragma unroll
        for (int s = 0; s < 4; ++s) {
            #pragma unroll
            for (int f = 0; f < 8; ++f) {
                int ba = ((ch * 128 + f * 16 + c15) * 512) + s * 64 + kch * 16;
                ba ^= ((c15 & 7) << 4);
                s16x8 bfrag = *reinterpret_cast<const s16x8*>(lds_b + ba);
                acc[f] = __builtin_amdgcn_mfma_f32_16x16x32_bf16(afrag[s], bfrag,
                                                                 acc[f], 0, 0, 0);
            }
        }

        // ---- convert batch 2 -> afrag[4..7] ----
        #pragma unroll
        for (int s4 = 0; s4 < 4; ++s4) {
            f32x4 xa = xv2[2 * s4], xb = xv2[2 * s4 + 1];
            float t0 = xa[0]*xa[0] + xa[1]*xa[1];
            float t1 = xa[2]*xa[2] + xa[3]*xa[3];
            float t2 = xb[0]*xb[0] + xb[1]*xb[1];
            float t3 = xb[2]*xb[2] + xb[3]*xb[3];
            p[s4] += (t0 + t1) + (t2 + t3);
            int s = 4 + s4;
            afrag[s][0] = (short)f2bf(xa[0]); afrag[s][1] = (short)f2bf(xa[1]);
            afrag[s][2] = (short)f2bf(xa[2]); afrag[s][3] = (short)f2bf(xa[3]);
            afrag[s][4] = (short)f2bf(xb[0]); afrag[s][5] = (short)f2bf(xb[1]);
            afrag[s][6] = (short)f2bf(xb[2]); afrag[s][7] = (short)f2bf(xb[3]);
        }

        #pragma unroll
        for (int s = 4; s < 8; ++s) {
            #pragma unroll
            for (int f = 0; f < 8; ++f) {
                int ba = ((ch * 128 + f * 16 + c15) * 512) + s * 64 + kch * 16;
                ba ^= ((c15 & 7) << 4);
                s16x8 bfrag = *reinterpret_cast<const s16x8*>(lds_b + ba);
                acc[f] = __builtin_amdgcn_mfma_f32_16x16x32_bf16(afrag[s], bfrag,
                                                                 acc[f], 0, 0, 0);
            }
        }

        // ---- prefetch next strip's batch 1: flies through epilogue+sync ----
        if (k + 1 < nk) {
            const float* xn = xrow(k + 1);
            #pragma unroll
            for (int i = 0; i < 8; ++i)
                xv1[i] = *reinterpret_cast<const f32x4*>(xn + (i >> 1) * 32 + (i & 1) * 4);
        }

        // ---- epilogue: student-t + 128-col partial row sums ----
        float xsq = (p[0] + p[1]) + (p[2] + p[3]);
        xsq += __shfl_xor(xsq, 16);
        xsq += __shfl_xor(xsq, 32);
        // lane l now holds xsq of row row0t + (l&15)

        float psum[4];
        #pragma unroll
        for (int r = 0; r < 4; ++r) {
            float xrr = __shfl(xsq, kch * 4 + r);
            float s = 0.f;
            #pragma unroll
            for (int f = 0; f < 8; ++f) {
                float d2 = xrr - 2.0f * acc[f][r] + cs[f];
                float qv = __builtin_amdgcn_rcpf(1.0f + d2);  // ALPHA=1 -> exp==1
                acc[f][r] = qv;
                s += qv;
            }
            s += __shfl_xor(s, 1);
            s += __shfl_xor(s, 2);
            s += __shfl_xor(s, 4);
            s += __shfl_xor(s, 8);
            psum[r] = s;   // sum over this wave's 128 cols, row kch*4+r
        }

        // ---- pairwise handshake (no block barrier, no vmcnt drain) ----
        if (c15 == 0) {
            #pragma unroll
            for (int r = 0; r < 4; ++r)
                ls_sum[k & 1][ch][rg][kch * 4 + r] = psum[r];
        }
        asm volatile("s_waitcnt lgkmcnt(0)" ::: "memory");  // sums visible
        if (lane == 0)
            __atomic_store_n(&ls_flag[ch][rg], k + 1, __ATOMIC_RELAXED);

        volatile int* pf = (volatile int*)&ls_flag[ch ^ 1][rg];
        while (*pf <= k) { }
        asm volatile("" ::: "memory");   // no hoisting of sum reads above spin

        #pragma unroll
        for (int r = 0; r < 4; ++r) {
            float other = ls_sum[k & 1][ch ^ 1][rg][kch * 4 + r];
            float inv = __builtin_amdgcn_rcpf(psum[r] + other);
            const size_t orow = (size_t)(row0t + kch * 4 + r) * KCL;
            #pragma unroll
            for (int f = 0; f < 8; ++f) {
                __builtin_nontemporal_store(acc[f][r] * inv,
                                            &out[orow + ch * 128 + f * 16 + c15]);
            }
        }
    }
}

extern "C" void kernel_launch(void* const* d_in, const int* in_sizes, int n_in,
                              void* d_out, int out_size, void* d_ws, size_t ws_size,
                              hipStream_t stream) {
    const float* x        = (const float*)d_in[0];
    const float* clusters = (const float*)d_in[1];
    float* out = (float*)d_out;

    // ws layout: [0, 128KB) clusters as bf16 ; [128KB, +1KB) c_sq f32
    unsigned short* cb  = (unsigned short*)d_ws;
    float*          csq = (float*)((char*)d_ws + (size_t)KCL * DDIM * sizeof(unsigned short));

    prep_kernel<<<KCL, 64, 0, stream>>>(clusters, cb, csq);
    fused_kernel<<<GRID, 768, 0, stream>>>(x, cb, csq, out);
}

// Round 14
// 253.491 us; speedup vs baseline: 1.2644x; 1.2644x over previous
//
#include <hip/hip_runtime.h>
#include <hip/hip_bf16.h>

// q = rownorm( 1 / (1 + ||x - c||^2) ), ALPHA=1
// x: (262144, 256) f32 ; clusters: (256, 256) f32 ; out: (262144, 256) f32
//
// R14: 3 waves/SIMD with a body that FITS the 85-arch-reg cap.
// Allocator model (calibrated R2..R13): launch_bounds => waves/SIMD target
// {1,2,3,4} => unified budget {512,256,170,128} => hard 50/50 arch/AGPR
// split => arch cap {256,128,85,64}. (768,2) rounds up to the 12-wave block
// quantum = 3 waves/SIMD => 85 arch. R13's body needed ~124 => spilled.
// Diet here: single reused xv[8] (32) + HALF-afrag pipeline (afA[4]/afB[4],
// 16 each, never both+xv at peak) + cast-based bf16 conversion (cvt_pk able)
// => peak arch ~80. acc[8]=32 lives in the 85-AGPR half. s_setprio(1)
// around MFMA clusters (free-running waves = role diversity, T5 regime).

#define NROWS 262144
#define DDIM  256
#define KCL   256
#define GRID  256
#define PPB   6                        // pairs per block (12 waves)
#define NPAIRS (GRID * PPB)            // 1536
#define NSTRIPS (NROWS / 16)           // 16384
#define BASEK (NSTRIPS / NPAIRS)       // 10
#define EXTRA (NSTRIPS % NPAIRS)       // first 1024 pairs get one extra strip

using f32x4  = __attribute__((ext_vector_type(4))) float;
using s16x8  = __attribute__((ext_vector_type(8))) short;

__device__ inline unsigned short f2bf(float f) {
    // round-to-nearest-even f32 -> bf16 (prep kernel only)
    unsigned int u = __float_as_uint(f);
    u += 0x7fffu + ((u >> 16) & 1u);
    return (unsigned short)(u >> 16);
}

__device__ inline short bfc(float f) {
    // cast-based conversion: compiler can pair these into v_cvt_pk_bf16_f32
    return (short)__bfloat16_as_ushort(__float2bfloat16(f));
}

// One wave per cluster row: convert to bf16, compute ||c||^2.
__global__ void prep_kernel(const float* __restrict__ clusters,
                            unsigned short* __restrict__ cb,
                            float* __restrict__ csq) {
    int k    = blockIdx.x;
    int lane = threadIdx.x;  // 64 threads
    const float* row = clusters + (size_t)k * DDIM;
    float4 a = *reinterpret_cast<const float4*>(row + lane * 4);
    ushort4 b;
    b.x = f2bf(a.x); b.y = f2bf(a.y); b.z = f2bf(a.z); b.w = f2bf(a.w);
    *reinterpret_cast<ushort4*>(cb + (size_t)k * DDIM + lane * 4) = b;
    float ss = a.x*a.x + a.y*a.y + a.z*a.z + a.w*a.w;
    #pragma unroll
    for (int m = 1; m < 64; m <<= 1) ss += __shfl_xor(ss, m);
    if (lane == 0) csq[k] = ss;
}

// 12 waves/block: wave w -> rg = w>>1 (pair 0..5), ch = w&1 (col half).
// Pair g = blockIdx*6+rg handles strips g + 1536*k (16 rows each);
// within the pair, wave computes 16 rows x cols [ch*128, +128).
// A-frag: lane holds x[row + (l&15)][s*32 + (l>>4)*8 + j], j=0..7
// B-frag: lane holds c[ch*128 + f*16 + (l&15)][s*32 + (l>>4)*8 + j], f=0..7
// C/D   : col = l&15, row = (l>>4)*4 + reg   [verified layout, m89]
__global__ __launch_bounds__(768, 2) void fused_kernel(
    const float* __restrict__ x,
    const unsigned short* __restrict__ cb,
    const float* __restrict__ csq,
    float* __restrict__ out) {

    __shared__ char  lds_b[KCL * DDIM * 2];   // 128 KB: full B, swizzled
    __shared__ float ls_sum[2][2][PPB][16];   // [k&1][ch][rg][row] partials
    __shared__ int   ls_flag[2][PPB];         // [ch][rg] strips-completed

    const int tid  = threadIdx.x;
    const int lane = tid & 63;
    const int wave = tid >> 6;               // 0..11
    const int rg   = wave >> 1;              // 0..5
    const int ch   = wave & 1;               // 0..1
    const int c15  = lane & 15;
    const int kch  = lane >> 4;              // 0..3

    const int g  = blockIdx.x * PPB + rg;          // global pair id
    const int nk = BASEK + (g < EXTRA ? 1 : 0);    // strips for this pair

    // ---- stage full B into LDS (waves 0..7; linear dest, swizzled src) ----
    if (wave < 8) {
        #pragma unroll
        for (int it = 0; it < 16; ++it) {
            int slot = it * 8192 + tid * 16;
            int src  = slot ^ (((slot >> 9) & 7) << 4);
            __builtin_amdgcn_global_load_lds(
                (const __attribute__((address_space(1))) unsigned int*)((const char*)cb + src),
                (__attribute__((address_space(3))) unsigned int*)(lds_b + slot),
                16, 0, 0);
        }
    }

    if (tid < 2 * PPB) ((int*)ls_flag)[tid] = 0;

    // csq fragment for this wave's col half (8 regs)
    float cs[8];
    #pragma unroll
    for (int f = 0; f < 8; ++f) cs[f] = csq[ch * 128 + f * 16 + c15];

    __syncthreads();   // drains vmcnt; B + flags ready (only block barrier)

    // per-lane x base for strip iteration k
    auto xrow = [&](int k) -> const float* {
        return x + (size_t)((g + NPAIRS * k) * 16 + c15) * DDIM + kch * 8;
    };

    f32x4 xv[8];   // SINGLE reused load buffer (32 regs) — the register diet

    // ---- prologue: issue strip 0's first k-half (flies under B staging) ----
    {
        const float* xr = xrow(0);
        #pragma unroll
        for (int i = 0; i < 8; ++i)
            xv[i] = *reinterpret_cast<const f32x4*>(xr + (i >> 1) * 32 + (i & 1) * 4);
    }

    #pragma unroll 1
    for (int k = 0; k < nk; ++k) {
        const int row0t = (g + NPAIRS * k) * 16;
        const float* xr = xrow(k);

        float p0 = 0.f, p1 = 0.f;

        // ---- convert half 1 (k 0..127) -> afA[0..3]; xv dies ----
        s16x8 afA[4];
        #pragma unroll
        for (int s4 = 0; s4 < 4; ++s4) {
            f32x4 xa = xv[2 * s4], xb = xv[2 * s4 + 1];
            float t0 = xa[0]*xa[0] + xa[1]*xa[1];
            float t1 = xa[2]*xa[2] + xa[3]*xa[3];
            float t2 = xb[0]*xb[0] + xb[1]*xb[1];
            float t3 = xb[2]*xb[2] + xb[3]*xb[3];
            if (s4 & 1) p1 += (t0 + t1) + (t2 + t3);
            else        p0 += (t0 + t1) + (t2 + t3);
            afA[s4][0] = bfc(xa[0]); afA[s4][1] = bfc(xa[1]);
            afA[s4][2] = bfc(xa[2]); afA[s4][3] = bfc(xa[3]);
            afA[s4][4] = bfc(xb[0]); afA[s4][5] = bfc(xb[1]);
            afA[s4][6] = bfc(xb[2]); afA[s4][7] = bfc(xb[3]);
        }

        // ---- reload xv with half 2 (k 128..255); MFMA s0-3 covers latency ----
        #pragma unroll
        for (int i = 0; i < 8; ++i) {
            int ii = 8 + i;
            xv[i] = *reinterpret_cast<const f32x4*>(xr + (ii >> 1) * 32 + (ii & 1) * 4);
        }

        f32x4 acc[8];
        #pragma unroll
        for (int f = 0; f < 8; ++f) acc[f] = (f32x4){0.f, 0.f, 0.f, 0.f};

        __builtin_amdgcn_s_setprio(1);
        #pragma unroll
        for (int s = 0; s < 4; ++s) {
            #pragma unroll
            for (int f = 0; f < 8; ++f) {
                int ba = ((ch * 128 + f * 16 + c15) * 512) + s * 64 + kch * 16;
                ba ^= ((c15 & 7) << 4);
                s16x8 bfrag = *reinterpret_cast<const s16x8*>(lds_b + ba);
                acc[f] = __builtin_amdgcn_mfma_f32_16x16x32_bf16(afA[s], bfrag,
                                                                 acc[f], 0, 0, 0);
            }
        }
        __builtin_amdgcn_s_setprio(0);

        // ---- convert half 2 -> afB[0..3]; xv dies ----
        s16x8 afB[4];
        #pragma unroll
        for (int s4 = 0; s4 < 4; ++s4) {
            f32x4 xa = xv[2 * s4], xb = xv[2 * s4 + 1];
            float t0 = xa[0]*xa[0] + xa[1]*xa[1];
            float t1 = xa[2]*xa[2] + xa[3]*xa[3];
            float t2 = xb[0]*xb[0] + xb[1]*xb[1];
            float t3 = xb[2]*xb[2] + xb[3]*xb[3];
            if (s4 & 1) p1 += (t0 + t1) + (t2 + t3);
            else        p0 += (t0 + t1) + (t2 + t3);
            afB[s4][0] = bfc(xa[0]); afB[s4][1] = bfc(xa[1]);
            afB[s4][2] = bfc(xa[2]); afB[s4][3] = bfc(xa[3]);
            afB[s4][4] = bfc(xb[0]); afB[s4][5] = bfc(xb[1]);
            afB[s4][6] = bfc(xb[2]); afB[s4][7] = bfc(xb[3]);
        }

        // ---- reload xv with NEXT strip's half 1 (flies through MFMA+epilogue) ----
        if (k + 1 < nk) {
            const float* xn = xrow(k + 1);
            #pragma unroll
            for (int i = 0; i < 8; ++i)
                xv[i] = *reinterpret_cast<const f32x4*>(xn + (i >> 1) * 32 + (i & 1) * 4);
        }

        __builtin_amdgcn_s_setprio(1);
        #pragma unroll
        for (int s = 4; s < 8; ++s) {
            #pragma unroll
            for (int f = 0; f < 8; ++f) {
                int ba = ((ch * 128 + f * 16 + c15) * 512) + s * 64 + kch * 16;
                ba ^= ((c15 & 7) << 4);
                s16x8 bfrag = *reinterpret_cast<const s16x8*>(lds_b + ba);
                acc[f] = __builtin_amdgcn_mfma_f32_16x16x32_bf16(afB[s - 4], bfrag,
                                                                 acc[f], 0, 0, 0);
            }
        }
        __builtin_amdgcn_s_setprio(0);

        // ---- epilogue: student-t + 128-col partial row sums ----
        float xsq = p0 + p1;
        xsq += __shfl_xor(xsq, 16);
        xsq += __shfl_xor(xsq, 32);
        // lane l now holds xsq of row row0t + (l&15)

        float psum[4];
        #pragma unroll
        for (int r = 0; r < 4; ++r) {
            float xrr = __shfl(xsq, kch * 4 + r);
            float s = 0.f;
            #pragma unroll
            for (int f = 0; f < 8; ++f) {
                float d2 = xrr - 2.0f * acc[f][r] + cs[f];
                float qv = __builtin_amdgcn_rcpf(1.0f + d2);  // ALPHA=1 -> exp==1
                acc[f][r] = qv;
                s += qv;
            }
            s += __shfl_xor(s, 1);
            s += __shfl_xor(s, 2);
            s += __shfl_xor(s, 4);
            s += __shfl_xor(s, 8);
            psum[r] = s;   // sum over this wave's 128 cols, row kch*4+r
        }

        // ---- pairwise handshake (no block barrier, no vmcnt drain) ----
        if (c15 == 0) {
            #pragma unroll
            for (int r = 0; r < 4; ++r)
                ls_sum[k & 1][ch][rg][kch * 4 + r] = psum[r];
        }
        asm volatile("s_waitcnt lgkmcnt(0)" ::: "memory");  // sums visible
        if (lane == 0)
            __atomic_store_n(&ls_flag[ch][rg], k + 1, __ATOMIC_RELAXED);

        volatile int* pf = (volatile int*)&ls_flag[ch ^ 1][rg];
        while (*pf <= k) { }
        asm volatile("" ::: "memory");   // no hoisting of sum reads above spin

        #pragma unroll
        for (int r = 0; r < 4; ++r) {
            float other = ls_sum[k & 1][ch ^ 1][rg][kch * 4 + r];
            float inv = __builtin_amdgcn_rcpf(psum[r] + other);
            const size_t orow = (size_t)(row0t + kch * 4 + r) * KCL;
            #pragma unroll
            for (int f = 0; f < 8; ++f) {
                __builtin_nontemporal_store(acc[f][r] * inv,
                                            &out[orow + ch * 128 + f * 16 + c15]);
            }
        }
    }
}

extern "C" void kernel_launch(void* const* d_in, const int* in_sizes, int n_in,
                              void* d_out, int out_size, void* d_ws, size_t ws_size,
                              hipStream_t stream) {
    const float* x        = (const float*)d_in[0];
    const float* clusters = (const float*)d_in[1];
    float* out = (float*)d_out;

    // ws layout: [0, 128KB) clusters as bf16 ; [128KB, +1KB) c_sq f32
    unsigned short* cb  = (unsigned short*)d_ws;
    float*          csq = (float*)((char*)d_ws + (size_t)KCL * DDIM * sizeof(unsigned short));

    prep_kernel<<<KCL, 64, 0, stream>>>(clusters, cb, csq);
    fused_kernel<<<GRID, 768, 0, stream>>>(x, cb, csq, out);
}